// Round 13
// baseline (89.322 us; speedup 1.0000x reference)
//
#include <hip/hip_runtime.h>
#include <hip/hip_bf16.h>

// out[t,z] = sum_i f[t,i] * ( sum_j a[t,j] * C[i,j,z] )
// R13 = R10's best-measured main (26 us, 12 waves/CU plateau = ~36% matrix-pipe,
// the documented m97-structure ceiling) with the reduce pass eliminated:
//  - split-K (kp=8) resolved via fp32 atomicAdd into out (no partials, no reduce)
//  - out zeroed by 8 extra prep blocks (no separate memset dispatch)
//  - pipeline: 2 dispatches (prep, main) instead of 4
// Main: wave tile 64x16, block 4 waves (2mg x 2zg), grid 1024 = 32mt x 4zp x 8kp,
// kp=bid&7 -> XCD-affine CT chunk; launch_bounds(256,3) -> 3 waves/SIMD.
// ws: [0,4MB) CTf bf16 [i][z>>4][j>>3][z&15][j&7]; [4,5MB) APK bf16
// [t>>4][ks][lk][lm][8k] — every hot wave-load is ONE contiguous 1 KB segment.

typedef __attribute__((ext_vector_type(8))) short bf16x8;
typedef __attribute__((ext_vector_type(4))) float f32x4;

__device__ __forceinline__ unsigned pkbf16(float x, float y) {
    __hip_bfloat162 h = __float22bfloat162_rn(make_float2(x, y));
    unsigned u; __builtin_memcpy(&u, &h, sizeof(u));
    return u;
}

// ---------- prep: transpose C->CTf (bid<512) + pack a->APK (512..767)
// ---------- + zero out (768..775) ----------
__global__ __launch_bounds__(256) void cooc_prep(
    const float* __restrict__ Cc, const float* __restrict__ fa,
    ushort* __restrict__ CT, ushort* __restrict__ APK, float* __restrict__ out)
{
    const int bid = blockIdx.x;
    const int t = threadIdx.x;
    if (bid < 512) {
        __shared__ float tile[32][132];
        const int i  = bid >> 2;
        const int j0 = (bid & 3) * 32;
        {
            const int jj = t >> 3;
            const int zb = (t & 7) * 16;
            const float* src = Cc + (size_t)i * 16384 + (size_t)(j0 + jj) * 128 + zb;
            #pragma unroll
            for (int k = 0; k < 4; ++k)
                *(float4*)&tile[jj][zb + k * 4] = *(const float4*)(src + k * 4);
        }
        __syncthreads();
        {
            const int z = t >> 1;
            const int h = t & 1;
            unsigned o[8];
            #pragma unroll
            for (int p = 0; p < 8; ++p)
                o[p] = pkbf16(tile[h * 16 + 2 * p][z], tile[h * 16 + 2 * p + 1][z]);
            const int c0 = (j0 >> 3) + h * 2;
            ushort* dst = CT + (size_t)i * 16384 + (size_t)(z >> 4) * 2048
                             + (size_t)c0 * 128 + (z & 15) * 8;
            *(uint4*)dst         = make_uint4(o[0], o[1], o[2], o[3]);
            *(uint4*)(dst + 128) = make_uint4(o[4], o[5], o[6], o[7]);
        }
    } else if (bid < 768) {
        const int g = bid - 512;           // 0..255: 16-row group
        const int ks = t >> 6, lk = (t >> 4) & 3, lm = t & 15;
        const float* src = fa + (size_t)(g * 16 + lm) * 256 + 128 + ks * 32 + lk * 8;
        float4 q0 = *(const float4*)src;
        float4 q1 = *(const float4*)(src + 4);
        *(uint4*)(APK + (size_t)g * 2048 + t * 8) =
            make_uint4(pkbf16(q0.x, q0.y), pkbf16(q0.z, q0.w),
                       pkbf16(q1.x, q1.y), pkbf16(q1.z, q1.w));
    } else {
        // zero out: 8 blocks x 256 thr x 64 float4 = 2 MiB
        float4* o4 = (float4*)out;
        const size_t base = (size_t)(bid - 768) * 256 + t;
        const float4 z4 = {0.f, 0.f, 0.f, 0.f};
        #pragma unroll
        for (int k = 0; k < 64; ++k)
            o4[base + (size_t)k * 2048] = z4;
    }
}

// ---------- main (R10 verbatim except atomic epilogue) ----------
__global__ __launch_bounds__(256, 3) void cooc_main(
    const float* __restrict__ fa, const ushort* __restrict__ CT,
    const ushort* __restrict__ APK, float* __restrict__ out)
{
    __shared__ float f_lds[16][128];       // 8 KB: f[i_local][row]

    const int bid = blockIdx.x;
    const int kp = bid & 7, zp = (bid >> 3) & 3, mtile = bid >> 5;
    const int t0 = mtile * 128, i0 = kp * 16;
    const int tid = threadIdx.x, lane = tid & 63, wv = tid >> 6;
    const int mg = wv >> 1, zg = wv & 1;   // 64-row group, 16-z group
    const int lm = lane & 15, lk = lane >> 4;

    // stage f -> LDS (transposed [i][row])
    {
        const int row = tid & 127;
        const int sh = (tid >> 7) * 8;
        const float* fp = fa + (size_t)(t0 + row) * 256 + i0 + sh;
        float4 v0 = *(const float4*)fp;
        float4 v1 = *(const float4*)(fp + 4);
        f_lds[sh + 0][row] = v0.x; f_lds[sh + 1][row] = v0.y;
        f_lds[sh + 2][row] = v0.z; f_lds[sh + 3][row] = v0.w;
        f_lds[sh + 4][row] = v1.x; f_lds[sh + 5][row] = v1.y;
        f_lds[sh + 6][row] = v1.z; f_lds[sh + 7][row] = v1.w;
    }

    // A fragments: 16 contiguous 1 KB wave-loads (rows t0 + mg*64 .. +63)
    bf16x8 a_pk[4][4];                     // 64 regs
    {
        const ushort* ap = APK + (size_t)((t0 >> 4) + mg * 4) * 2048 + lane * 8;
        #pragma unroll
        for (int m = 0; m < 4; ++m)
            #pragma unroll
            for (int ks = 0; ks < 4; ++ks)
                a_pk[m][ks] = *(const bf16x8*)(ap + (size_t)m * 2048 + ks * 512);
    }
    __syncthreads();   // f_lds ready; only barrier

    // B source (contiguous): CTf + i*16384 + (zp*2+zg)*2048 + lane*8
    const ushort* bsrc = CT + (size_t)i0 * 16384
                            + (size_t)(zp * 2 + zg) * 2048 + lane * 8;

    // prime depth-2 prefetch: s=0 -> B[0], s=1 -> B[1]
    bf16x8 B[2][4];
    #pragma unroll
    for (int ks = 0; ks < 4; ++ks) {
        B[0][ks] = *(const bf16x8*)(bsrc + ks * 512);
        B[1][ks] = *(const bf16x8*)(bsrc + 16384 + ks * 512);
    }

    float acc[4][4];
    #pragma unroll
    for (int m = 0; m < 4; ++m)
        #pragma unroll
        for (int r = 0; r < 4; ++r) acc[m][r] = 0.f;

    #pragma unroll 2
    for (int s = 0; s < 16; ++s) {
        const int cur = s & 1;

        // 4 independent MFMA chains, ks-outer (dep distance 4)
        f32x4 g[4];
        #pragma unroll
        for (int m = 0; m < 4; ++m) g[m] = (f32x4){0.f, 0.f, 0.f, 0.f};
        #pragma unroll
        for (int ks = 0; ks < 4; ++ks)
            #pragma unroll
            for (int m = 0; m < 4; ++m)
                g[m] = __builtin_amdgcn_mfma_f32_16x16x32_bf16(
                    a_pk[m][ks], B[cur][ks], g[m], 0, 0, 0);

        // reload B[cur] with slab s+2 (issued after consumption; ~2-slab cover)
        if (s < 14) {
            const ushort* p = bsrc + (size_t)(s + 2) * 16384;
            #pragma unroll
            for (int ks = 0; ks < 4; ++ks)
                B[cur][ks] = *(const bf16x8*)(p + ks * 512);
        }

        // f read + fold
        float4 f4[4];
        #pragma unroll
        for (int m = 0; m < 4; ++m)
            f4[m] = *(const float4*)&f_lds[s][mg * 64 + m * 16 + lk * 4];
        #pragma unroll
        for (int m = 0; m < 4; ++m) {
            acc[m][0] += f4[m].x * g[m][0];
            acc[m][1] += f4[m].y * g[m][1];
            acc[m][2] += f4[m].z * g[m][2];
            acc[m][3] += f4[m].w * g[m][3];
        }
    }

    // epilogue: split-K resolved via device-scope atomics (C/D col=lm, row=lk*4+r)
    const int col = zp * 32 + zg * 16 + lm;
    #pragma unroll
    for (int m = 0; m < 4; ++m)
        #pragma unroll
        for (int r = 0; r < 4; ++r) {
            const int row = t0 + mg * 64 + m * 16 + lk * 4 + r;
            atomicAdd(&out[(size_t)row * 128 + col], acc[m][r]);
        }
}

// ---------- defensive naive fallback (never taken with real ws sizes) ----------
__global__ __launch_bounds__(128) void cooc_naive(
    const float* __restrict__ fa, const float* __restrict__ Cc,
    float* __restrict__ out)
{
    const int tk = blockIdx.x;     // token
    const int z  = threadIdx.x;    // output col
    const float* f = fa + (size_t)tk * 256;
    const float* a = f + 128;
    float s = 0.f;
    for (int i = 0; i < 128; ++i) {
        const float fi = f[i];
        const float* cr = Cc + (size_t)i * 16384 + z;
        float t = 0.f;
        for (int j = 0; j < 128; ++j) t += a[j] * cr[(size_t)j * 128];
        s += fi * t;
    }
    out[(size_t)tk * 128 + z] = s;
}

extern "C" void kernel_launch(void* const* d_in, const int* in_sizes, int n_in,
                              void* d_out, int out_size, void* d_ws, size_t ws_size,
                              hipStream_t stream) {
    const float* fa = (const float*)d_in[0];   // (4096,256): [:,0:128]=f, [:,128:256]=a
    const float* Cc = (const float*)d_in[1];   // (128,128,128)
    float* out = (float*)d_out;                // (4096,128)

    const size_t CTSZ = (size_t)128 * 128 * 128 * 2;   // 4 MiB
    const size_t APSZ = (size_t)4096 * 128 * 2;        // 1 MiB

    if (ws_size >= CTSZ + APSZ) {
        ushort* CT  = (ushort*)d_ws;
        ushort* APK = (ushort*)((char*)d_ws + CTSZ);
        cooc_prep<<<776, 256, 0, stream>>>(Cc, fa, CT, APK, out);
        cooc_main<<<1024, 256, 0, stream>>>(fa, CT, APK, out);
    } else {
        cooc_naive<<<4096, 128, 0, stream>>>(fa, Cc, out);
    }
}